// Round 1
// baseline (105.129 us; speedup 1.0000x reference)
//
#include <hip/hip_runtime.h>
#include <math.h>

#define NBINS 15
#define BLK 256

// One block per row. Single streaming pass:
//   m   = row max
//   s   = sum exp(x - m)   (online rescale)
//   m2  = max{ x_i : x_i < x_t }  (logit-space equivalent of probs < p_k)
__global__ __launch_bounds__(BLK) void row_loss_kernel(
    const float* __restrict__ inp,
    const int* __restrict__ target,
    const float* __restrict__ uppers,
    const float* __restrict__ gammas,
    float* __restrict__ row_loss,
    int C)
{
    const int row = blockIdx.x;
    const float* __restrict__ x = inp + (size_t)row * (size_t)C;
    const float xt = x[target[row]];   // broadcast load (same addr all lanes)

    float m  = -INFINITY;
    float s  = 0.0f;
    float m2 = -INFINITY;

    const int nvec = C >> 2;
    const float4* __restrict__ xv = (const float4*)x;

    for (int i = threadIdx.x; i < nvec; i += BLK) {
        float4 v = xv[i];
        float f;
        f = v.x; if (f > m) { s *= __expf(m - f); m = f; } s += __expf(f - m); if (f < xt) m2 = fmaxf(m2, f);
        f = v.y; if (f > m) { s *= __expf(m - f); m = f; } s += __expf(f - m); if (f < xt) m2 = fmaxf(m2, f);
        f = v.z; if (f > m) { s *= __expf(m - f); m = f; } s += __expf(f - m); if (f < xt) m2 = fmaxf(m2, f);
        f = v.w; if (f > m) { s *= __expf(m - f); m = f; } s += __expf(f - m); if (f < xt) m2 = fmaxf(m2, f);
    }
    // scalar tail (C % 4 != 0 safety; C=32000 -> no-op)
    for (int i = (nvec << 2) + threadIdx.x; i < C; i += BLK) {
        float f = x[i];
        if (f > m) { s *= __expf(m - f); m = f; }
        s += __expf(f - m);
        if (f < xt) m2 = fmaxf(m2, f);
    }

    // wave-64 butterfly reduce of (m, s) and m2
    #pragma unroll
    for (int off = 32; off > 0; off >>= 1) {
        float om  = __shfl_xor(m,  off);
        float os  = __shfl_xor(s,  off);
        float om2 = __shfl_xor(m2, off);
        float M = fmaxf(m, om);
        s = s * __expf(m - M) + os * __expf(om - M);
        m = M;
        m2 = fmaxf(m2, om2);
    }

    __shared__ float sm[4], ss[4], sm2[4];
    const int wid  = threadIdx.x >> 6;
    const int lane = threadIdx.x & 63;
    if (lane == 0) { sm[wid] = m; ss[wid] = s; sm2[wid] = m2; }
    __syncthreads();

    if (threadIdx.x == 0) {
        m = sm[0]; s = ss[0]; m2 = sm2[0];
        #pragma unroll
        for (int w = 1; w < 4; ++w) {
            float M = fmaxf(m, sm[w]);
            s = s * __expf(m - M) + ss[w] * __expf(sm[w] - M);
            m = M;
            m2 = fmaxf(m2, sm2[w]);
        }
        const float logZ  = m + __logf(s);
        const float logpk = xt - logZ;
        const float pk    = __expf(logpk);
        const float pj    = (m2 == -INFINITY) ? 0.0f : __expf(m2 - logZ);
        const float pt    = pk - pj;

        // searchsorted(uppers, pt, 'right') = count(uppers <= pt), clipped
        int idx = 0;
        #pragma unroll
        for (int j = 0; j < NBINS; ++j) idx += (uppers[j] <= pt) ? 1 : 0;
        if (idx > NBINS - 1) idx = NBINS - 1;

        const float gamma = gammas[idx];
        const float base  = 1.0f - pk + pj;
        row_loss[row] = -__powf(base, gamma) * logpk;
    }
}

// Deterministic final sum of N per-row losses (single block).
__global__ __launch_bounds__(BLK) void sum_kernel(
    const float* __restrict__ v, float* __restrict__ out, int n)
{
    float acc = 0.0f;
    for (int i = threadIdx.x; i < n; i += BLK) acc += v[i];
    #pragma unroll
    for (int off = 32; off > 0; off >>= 1) acc += __shfl_xor(acc, off);
    __shared__ float sacc[4];
    const int wid  = threadIdx.x >> 6;
    const int lane = threadIdx.x & 63;
    if (lane == 0) sacc[wid] = acc;
    __syncthreads();
    if (threadIdx.x == 0) out[0] = sacc[0] + sacc[1] + sacc[2] + sacc[3];
}

extern "C" void kernel_launch(void* const* d_in, const int* in_sizes, int n_in,
                              void* d_out, int out_size, void* d_ws, size_t ws_size,
                              hipStream_t stream) {
    const float* inp    = (const float*)d_in[0];
    const int*   target = (const int*)d_in[1];
    const float* uppers = (const float*)d_in[2];
    const float* gammas = (const float*)d_in[3];
    float* out = (float*)d_out;
    float* ws  = (float*)d_ws;

    const int N = in_sizes[1];            // 4096
    const int C = in_sizes[0] / N;        // 32000

    row_loss_kernel<<<N, BLK, 0, stream>>>(inp, target, uppers, gammas, ws, C);
    sum_kernel<<<1, BLK, 0, stream>>>(ws, out, N);
}